// Round 8
// baseline (221.403 us; speedup 1.0000x reference)
//
#include <hip/hip_runtime.h>
#include <hip/hip_bf16.h>
#include <stdint.h>

// Problem constants (fixed-shape problem)
#define HEADS 16
#define HDIM  64
#define DIMC  1024
#define INNER 1024
#define LSEQ  2048
#define BLM   4096   // B*L

typedef unsigned short u16;
typedef __attribute__((ext_vector_type(8))) short bf16x8;  // 8 bf16 = 4 VGPRs
typedef __attribute__((ext_vector_type(4))) float f32x4;

__device__ __forceinline__ u16 f2bf(float f) {
  union { float f; uint32_t u; } v; v.f = f;
  uint32_t u = v.u;
  return (u16)((u + 0x7fffu + ((u >> 16) & 1u)) >> 16);  // RNE
}
__device__ __forceinline__ uint32_t pack_bf2(float a, float b) {
  float2 f2; f2.x = a; f2.y = b;
  __hip_bfloat162 t = __float22bfloat162_rn(f2);
  union { __hip_bfloat162 h; uint32_t u; } c; c.h = t; return c.u;
}
// raw quarter-rate HW exp2 — avoids OCML's precise-path polynomial
__device__ __forceinline__ float fast_exp2(float x) {
  float r; asm("v_exp_f32 %0, %1" : "=v"(r) : "v"(x)); return r;
}

// async global->LDS, 16B per lane; LDS dest = wave-uniform base + lane*16
__device__ __forceinline__ void load_lds16(const void* g, void* l) {
  __builtin_amdgcn_global_load_lds(
      (const __attribute__((address_space(1))) uint32_t*)g,
      (__attribute__((address_space(3))) uint32_t*)l, 16, 0, 0);
}

// ---------------------------------------------------------------- cast x -> bf16
__global__ __launch_bounds__(256) void cast_bf16_k(const float* __restrict__ in,
                                                   u16* __restrict__ out, int n) {
  int i = (blockIdx.x * 256 + threadIdx.x) * 4;
  if (i < n) {
    float4 v = *(const float4*)(in + i);
    ushort4 o;
    o.x = f2bf(v.x); o.y = f2bf(v.y); o.z = f2bf(v.z); o.w = f2bf(v.w);
    *(ushort4*)(out + i) = o;
  }
}

// ------------------------------------------------- transpose+cast: [R][C]f32 -> [C][R]bf16
__global__ __launch_bounds__(256) void transpose_cast_k(const float* __restrict__ in,
                                                        u16* __restrict__ out,
                                                        int R, int C) {
  __shared__ float tile[32][33];
  int c0 = blockIdx.x * 32, r0 = blockIdx.y * 32;
  int j = threadIdx.x & 31, i0 = threadIdx.x >> 5;
#pragma unroll
  for (int p = 0; p < 4; ++p) {
    int i = i0 + p * 8;
    tile[i][j] = in[(size_t)(r0 + i) * C + (c0 + j)];
  }
  __syncthreads();
#pragma unroll
  for (int p = 0; p < 4; ++p) {
    int i = i0 + p * 8;
    out[(size_t)(c0 + i) * R + (r0 + j)] = f2bf(tile[j][i]);
  }
}

// ------------------------------------------------------------------ GEMM (B^T input)
// C[M][N] = A[M][K] @ Bt[N][K], bf16 in, fp32 accum. TMx128 tile, BK=64.
// EPI==1: store f32 (acc + bias[col] + resid[row][col]).
// EPI==2: QKV split: cols<2048 -> Cb (stride 2048, Q|K packed);
//         cols>=2048 are V -> transposed store into Vt[bh][d][l].
template <int EPI, int TM>
__global__ __launch_bounds__(256) void gemm_bt(const u16* __restrict__ A,
                                               const u16* __restrict__ Bt,
                                               u16* __restrict__ Cb,
                                               float* __restrict__ Cf,
                                               const float* __restrict__ bias,
                                               const float* __restrict__ resid,
                                               u16* __restrict__ Vt,
                                               int M, int N, int K) {
  constexpr int MI = TM / 32;  // A-frags per wave (wave m-extent = TM/2)
  __shared__ alignas(16) u16 As[TM * 64];
  __shared__ alignas(16) u16 Bs[128 * 64];
  const int tid = threadIdx.x;
  const int lane = tid & 63;
  const int w = tid >> 6;
  const int wm = w >> 1, wn = w & 1;
  const int m0 = blockIdx.y * TM, n0 = blockIdx.x * 128;
  const int ln = lane & 15, qq = lane >> 4;
  const f32x4 zero4 = {0.f, 0.f, 0.f, 0.f};

  f32x4 acc[MI][4];
#pragma unroll
  for (int i = 0; i < MI; ++i)
#pragma unroll
    for (int j = 0; j < 4; ++j) acc[i][j] = zero4;

  for (int kt = 0; kt < K; kt += 64) {
    __syncthreads();
    // rows of 64 bf16 = 8 chunks of 16B; dest chunk d holds global chunk
    // d ^ (r&7) so frag reads (chunk (ks*4+qq)^(r&7)) spread all banks.
#pragma unroll
    for (int p = 0; p < TM / 32; ++p) {
      int t = p * 256 + tid;
      int r = t >> 3;
      int cl = (t & 7) ^ (r & 7);
      load_lds16(A + (size_t)(m0 + r) * K + kt + cl * 8,
                 (char*)As + (p * 256 + w * 64) * 16);
    }
#pragma unroll
    for (int p = 0; p < 4; ++p) {
      int t = p * 256 + tid;
      int r = t >> 3;
      int cl = (t & 7) ^ (r & 7);
      load_lds16(Bt + (size_t)(n0 + r) * K + kt + cl * 8,
                 (char*)Bs + (p * 256 + w * 64) * 16);
    }
    __syncthreads();
#pragma unroll
    for (int ks = 0; ks < 2; ++ks) {
      bf16x8 af[MI], bfr[4];
#pragma unroll
      for (int i = 0; i < MI; ++i) {
        int ra = wm * (TM / 2) + i * 16 + ln;
        af[i] = *(const bf16x8*)(As + (ra * 8 + ((ks * 4 + qq) ^ (ra & 7))) * 8);
      }
#pragma unroll
      for (int j = 0; j < 4; ++j) {
        int rb = wn * 64 + j * 16 + ln;
        bfr[j] = *(const bf16x8*)(Bs + (rb * 8 + ((ks * 4 + qq) ^ (rb & 7))) * 8);
      }
#pragma unroll
      for (int i = 0; i < MI; ++i)
#pragma unroll
        for (int j = 0; j < 4; ++j)
          acc[i][j] = __builtin_amdgcn_mfma_f32_16x16x32_bf16(af[i], bfr[j],
                                                              acc[i][j], 0, 0, 0);
    }
  }

  // C/D layout (m89-verified): col = lane&15, row = (lane>>4)*4 + reg
#pragma unroll
  for (int i = 0; i < MI; ++i) {
#pragma unroll
    for (int j = 0; j < 4; ++j) {
      int col = n0 + wn * 64 + j * 16 + ln;
      if (EPI == 1) {
#pragma unroll
        for (int rr = 0; rr < 4; ++rr) {
          int row = m0 + wm * (TM / 2) + i * 16 + qq * 4 + rr;
          Cf[(size_t)row * N + col] =
              acc[i][j][rr] + bias[col] + resid[(size_t)row * N + col];
        }
      } else {  // EPI == 2
        if (col < 2048) {
#pragma unroll
          for (int rr = 0; rr < 4; ++rr) {
            int row = m0 + wm * (TM / 2) + i * 16 + qq * 4 + rr;
            Cb[(size_t)row * 2048 + col] = f2bf(acc[i][j][rr]);
          }
        } else {
          // V column: store transposed Vt[(b*16+h)*64+d][l], 4 consecutive l
          int dg = col - 2048;
          int hh = dg >> 6, dd = dg & 63;
          int l0 = (m0 & 2047) + wm * (TM / 2) + i * 16 + qq * 4;
          int bb = m0 >> 11;
          ushort4 pk;
          pk.x = f2bf(acc[i][j][0]); pk.y = f2bf(acc[i][j][1]);
          pk.z = f2bf(acc[i][j][2]); pk.w = f2bf(acc[i][j][3]);
          *(ushort4*)(Vt + (((size_t)bb * 16 + hh) * 64 + dd) * 2048 + l0) = pk;
        }
      }
    }
  }
}

// ------------------------------------------------------------------ flash attention (S^T form)
// R8: K/V double-buffer with COMPILE-TIME buffer pointers (phase A consumes
// buf0/prefetches buf1; phase B the reverse) — each barrier's vmcnt(0) drain
// lands on DMAs issued a full compute phase earlier. P buffer shrunk to
// [16][64] per wave via XOR unit-swizzle (u' = u ^ (q&7), unit = 16B):
// LDS = 16K (K) + 16K (V) + 8K (P) = 40960 B -> 4 blocks/CU retained.
// Static softmax (R7): no online max; per-lane partial sums, 2 shfls at end.
__global__ __launch_bounds__(256) void attn_fused(const u16* __restrict__ qk,
                                                  const u16* __restrict__ vt,
                                                  u16* __restrict__ outp) {
  const int qt = blockIdx.x & 31;
  const int h = (blockIdx.x >> 5) & 15;
  const int b = blockIdx.x >> 9;
  const int tid = threadIdx.x;
  const int lane = tid & 63;
  const int w = tid >> 6;
  const int ln = lane & 15, q4 = lane >> 4;
  const int l7 = ln & 7;
  const f32x4 zero4 = {0.f, 0.f, 0.f, 0.f};

  __shared__ alignas(16) u16 Ks[2][64 * 64];  // [buf][key][8 unit swz][8 d]
  __shared__ alignas(16) u16 Vs[2][64 * 64];  // [buf][d][8 unit swz][8 key]
  __shared__ alignas(16) u16 Ps[4][16 * 64];  // per-wave P^T, XOR unit-swizzled

  const size_t bh_tok = (size_t)b * LSEQ;
  const size_t vbase = ((size_t)b * 16 + h) * 64 * 2048;
  const int baseQ = h * HDIM;

  // Q fragment (B-operand: n=ln, k=q4*8+j (+32*ks)), scaled by log2e/8
  const float qscale = 0.125f * 1.44269504088896340736f;
  bf16x8 qf[2];
  {
    int row = qt * 64 + w * 16 + ln;
    const u16* p = qk + (bh_tok + row) * 2048 + baseQ;
#pragma unroll
    for (int ks = 0; ks < 2; ++ks) {
      bf16x8 v = *(const bf16x8*)(p + q4 * 8 + 32 * ks);
      bf16x8 o;
#pragma unroll
      for (int jj = 0; jj < 8; ++jj) {
        union { uint32_t u; float f; } cv; cv.u = ((uint32_t)(u16)v[jj]) << 16;
        o[jj] = (short)f2bf(cv.f * qscale);
      }
      qf[ks] = o;
    }
  }

  float lsum = 0.f;  // per-lane partial row sum (reduced once at the end)
  f32x4 o_acc[4];
#pragma unroll
  for (int dt = 0; dt < 4; ++dt) o_acc[dt] = zero4;

  u16* pw_base = &Ps[w][0];

  // DMA one 64-key tile: K [64 key][64 d] and V^T [64 d][64 key]
  auto prefetch = [&](int key0, u16* Kd, u16* Vd) {
#pragma unroll
    for (int iss = 0; iss < 2; ++iss) {
      int idx = iss * 256 + tid;
      int row = idx >> 3, c = idx & 7;
      int cl = c ^ (row & 7);
      load_lds16(qk + (bh_tok + key0 + row) * 2048 + 1024 + baseQ + cl * 8,
                 (char*)Kd + (iss * 256 + w * 64) * 16);
      load_lds16(vt + vbase + (size_t)row * 2048 + key0 + cl * 8,
                 (char*)Vd + (iss * 256 + w * 64) * 16);
    }
  };

  // compute one 64-key tile from (Kc, Vc)
  auto compute = [&](const u16* Kc, const u16* Vc) {
    // S^T[key][q] = K·Q^T : 4 key-tiles, 2 k-steps over d
    f32x4 S[4];
#pragma unroll
    for (int kt = 0; kt < 4; ++kt) {
      f32x4 a = zero4;
#pragma unroll
      for (int ks = 0; ks < 2; ++ks) {
        bf16x8 kf = *(const bf16x8*)(
            Kc + (((kt * 16 + ln) * 8 + ((ks * 4 + q4) ^ l7)) * 8));
        a = __builtin_amdgcn_mfma_f32_16x16x32_bf16(kf, qf[ks], a, 0, 0, 0);
      }
      S[kt] = a;
    }

    // static softmax: P = 2^S, accumulate per-lane partial sums only
#pragma unroll
    for (int kt = 0; kt < 4; ++kt)
#pragma unroll
      for (int r = 0; r < 4; ++r) {
        float p = fast_exp2(S[kt][r]);
        S[kt][r] = p;
        lsum += p;
      }

    // P^T (C-layout) -> per-wave LDS [q=ln][key], unit(16B)-swizzled
#pragma unroll
    for (int kt = 0; kt < 4; ++kt) {
      uint2 pd;
      pd.x = pack_bf2(S[kt][0], S[kt][1]);
      pd.y = pack_bf2(S[kt][2], S[kt][3]);
      int u = kt * 2 + (q4 >> 1);
      *(uint2*)(pw_base + ln * 64 + ((u ^ l7) * 8) + (q4 & 1) * 4) = pd;
    }
    asm volatile("s_waitcnt lgkmcnt(0)" ::: "memory");  // wave-local W->R fence

    bf16x8 pf0 = *(const bf16x8*)(pw_base + ln * 64 + (((0 * 4 + q4) ^ l7) * 8));
    bf16x8 pf1 = *(const bf16x8*)(pw_base + ln * 64 + (((1 * 4 + q4) ^ l7) * 8));

    // O^T[d][q] += V^T·P^T
#pragma unroll
    for (int dt = 0; dt < 4; ++dt) {
      bf16x8 va0 = *(const bf16x8*)(
          Vc + (((dt * 16 + ln) * 8 + ((0 * 4 + q4) ^ l7)) * 8));
      o_acc[dt] = __builtin_amdgcn_mfma_f32_16x16x32_bf16(va0, pf0, o_acc[dt], 0, 0, 0);
      bf16x8 va1 = *(const bf16x8*)(
          Vc + (((dt * 16 + ln) * 8 + ((1 * 4 + q4) ^ l7)) * 8));
      o_acc[dt] = __builtin_amdgcn_mfma_f32_16x16x32_bf16(va1, pf1, o_acc[dt], 0, 0, 0);
    }
  };

  // prologue: tile 0 -> buf 0
  prefetch(0, Ks[0], Vs[0]);

  for (int jp = 0; jp < 16; ++jp) {
    // phase A: consume buf0 (tile 2jp), prefetch tile 2jp+1 -> buf1
    __syncthreads();  // drains buf0 DMA (issued one compute phase ago)
    prefetch((2 * jp + 1) * 64, Ks[1], Vs[1]);
    compute(Ks[0], Vs[0]);
    // phase B: consume buf1, prefetch tile 2jp+2 -> buf0
    __syncthreads();  // drains buf1 DMA
    if (jp < 15) prefetch((2 * jp + 2) * 64, Ks[0], Vs[0]);
    compute(Ks[1], Vs[1]);
  }

  // final row-sum reduction (deferred): lanes 16/32 hold other key subsets
  lsum += __shfl_xor(lsum, 16);
  lsum += __shfl_xor(lsum, 32);
  float rl = 1.0f / lsum;

  // epilogue: O^T -> per-wave LDS [q=ln][d] (same unit swizzle) -> rows out
  asm volatile("s_waitcnt lgkmcnt(0)" ::: "memory");
#pragma unroll
  for (int dt = 0; dt < 4; ++dt) {
    uint2 pd;
    pd.x = pack_bf2(o_acc[dt][0] * rl, o_acc[dt][1] * rl);
    pd.y = pack_bf2(o_acc[dt][2] * rl, o_acc[dt][3] * rl);
    int u = dt * 2 + (q4 >> 1);
    *(uint2*)(pw_base + ln * 64 + ((u ^ l7) * 8) + (q4 & 1) * 4) = pd;
  }
  asm volatile("s_waitcnt lgkmcnt(0)" ::: "memory");
  // full-coverage read-out: 2 passes x 64 lanes x 8 u16 = 16 tokens x 64 d
#pragma unroll
  for (int half = 0; half < 2; ++half) {
    int rr = half * 8 + (lane >> 3);
    int ch = lane & 7;
    bf16x8 rowv = *(const bf16x8*)(pw_base + rr * 64 + ((ch ^ (rr & 7)) * 8));
    int tok = qt * 64 + w * 16 + rr;
    *(bf16x8*)(outp + (bh_tok + tok) * 1024 + baseQ + ch * 8) = rowv;
  }
}

// ------------------------------------------------------------------ LayerNorm rows
// one wave per row, 4 rows/block, shuffle-only reduction (no barrier).
__global__ __launch_bounds__(256) void ln_k(const float* __restrict__ res,
                                            const float* __restrict__ gamma,
                                            const float* __restrict__ beta,
                                            float* __restrict__ out) {
  int w = threadIdx.x >> 6, lane = threadIdx.x & 63;
  int row = blockIdx.x * 4 + w;
  const float* r = res + (size_t)row * DIMC;
  float4 v[4];
  float s = 0.f, ss = 0.f;
#pragma unroll
  for (int p = 0; p < 4; ++p) {
    v[p] = *(const float4*)(r + (p * 64 + lane) * 4);
    s += v[p].x + v[p].y + v[p].z + v[p].w;
    ss += v[p].x * v[p].x + v[p].y * v[p].y + v[p].z * v[p].z + v[p].w * v[p].w;
  }
#pragma unroll
  for (int off = 1; off < 64; off <<= 1) {
    s += __shfl_xor(s, off);
    ss += __shfl_xor(ss, off);
  }
  float mean = s * (1.0f / DIMC);
  float var = ss * (1.0f / DIMC) - mean * mean;
  float inv = rsqrtf(var + 1e-5f);
#pragma unroll
  for (int p = 0; p < 4; ++p) {
    int c = (p * 64 + lane) * 4;
    float4 g = *(const float4*)(gamma + c);
    float4 bt = *(const float4*)(beta + c);
    float4 o;
    o.x = (v[p].x - mean) * inv * g.x + bt.x;
    o.y = (v[p].y - mean) * inv * g.y + bt.y;
    o.z = (v[p].z - mean) * inv * g.z + bt.z;
    o.w = (v[p].w - mean) * inv * g.w + bt.w;
    *(float4*)(out + (size_t)row * DIMC + c) = o;
  }
}

extern "C" void kernel_launch(void* const* d_in, const int* in_sizes, int n_in,
                              void* d_out, int out_size, void* d_ws, size_t ws_size,
                              hipStream_t stream) {
  const float* x = (const float*)d_in[0];
  const float* w_qkv = (const float*)d_in[1];
  const float* w_out = (const float*)d_in[2];
  const float* b_out = (const float*)d_in[3];
  const float* gamma = (const float*)d_in[4];
  const float* beta = (const float*)d_in[5];
  float* outp = (float*)d_out;
  char* ws = (char*)d_ws;

  // ws layout (38 MB), aliasing by liveness:
  //   [0,8M):   xb (bf16 x)         -> attnout after GEMM1
  //   [8,14M):  wqkvT               -> woutT after GEMM1
  //   [14,30M): qk (bf16 4096x2048) -> res (f32 16MB) after attn
  //   [30,38M): vt (bf16 32x64x2048, V pre-transposed)
  u16* xb = (u16*)(ws);
  u16* wqkvT = (u16*)(ws + ((size_t)8 << 20));
  u16* qk = (u16*)(ws + ((size_t)14 << 20));
  u16* vt = (u16*)(ws + ((size_t)30 << 20));
  u16* attnout = (u16*)(ws);
  u16* woutT = (u16*)(ws + ((size_t)8 << 20));
  float* res = (float*)(ws + ((size_t)14 << 20));

  cast_bf16_k<<<4096, 256, 0, stream>>>(x, xb, BLM * DIMC);
  transpose_cast_k<<<dim3(96, 32), 256, 0, stream>>>(w_qkv, wqkvT, 1024, 3072);
  gemm_bt<2, 128><<<dim3(24, 32), 256, 0, stream>>>(xb, wqkvT, qk, nullptr,
                                                    nullptr, nullptr, vt,
                                                    BLM, 3072, 1024);
  transpose_cast_k<<<dim3(32, 32), 256, 0, stream>>>(w_out, woutT, 1024, 1024);
  attn_fused<<<1024, 256, 0, stream>>>(qk, vt, attnout);
  gemm_bt<1, 64><<<dim3(8, 64), 256, 0, stream>>>(attnout, woutT, nullptr, res,
                                                  b_out, x, nullptr,
                                                  BLM, 1024, 1024);
  ln_k<<<1024, 256, 0, stream>>>(res, gamma, beta, outp);
}

// Round 10
// 209.513 us; speedup vs baseline: 1.0568x; 1.0568x over previous
//
#include <hip/hip_runtime.h>
#include <hip/hip_bf16.h>
#include <stdint.h>

// Problem constants (fixed-shape problem)
#define HEADS 16
#define HDIM  64
#define DIMC  1024
#define INNER 1024
#define LSEQ  2048
#define BLM   4096   // B*L

typedef unsigned short u16;
typedef __attribute__((ext_vector_type(8))) short bf16x8;  // 8 bf16 = 4 VGPRs
typedef __attribute__((ext_vector_type(4))) float f32x4;

__device__ __forceinline__ u16 f2bf(float f) {
  union { float f; uint32_t u; } v; v.f = f;
  uint32_t u = v.u;
  return (u16)((u + 0x7fffu + ((u >> 16) & 1u)) >> 16);  // RNE
}
__device__ __forceinline__ uint32_t pack_bf2(float a, float b) {
  float2 f2; f2.x = a; f2.y = b;
  __hip_bfloat162 t = __float22bfloat162_rn(f2);
  union { __hip_bfloat162 h; uint32_t u; } c; c.h = t; return c.u;
}
// raw quarter-rate HW exp2 — avoids OCML's precise-path polynomial
__device__ __forceinline__ float fast_exp2(float x) {
  float r; asm("v_exp_f32 %0, %1" : "=v"(r) : "v"(x)); return r;
}

// async global->LDS, 16B per lane; LDS dest = wave-uniform base + lane*16
__device__ __forceinline__ void load_lds16(const void* g, void* l) {
  __builtin_amdgcn_global_load_lds(
      (const __attribute__((address_space(1))) uint32_t*)g,
      (__attribute__((address_space(3))) uint32_t*)l, 16, 0, 0);
}

// ---------------------------------------------------------------- cast x -> bf16
__global__ __launch_bounds__(256) void cast_bf16_k(const float* __restrict__ in,
                                                   u16* __restrict__ out, int n) {
  int i = (blockIdx.x * 256 + threadIdx.x) * 4;
  if (i < n) {
    float4 v = *(const float4*)(in + i);
    ushort4 o;
    o.x = f2bf(v.x); o.y = f2bf(v.y); o.z = f2bf(v.z); o.w = f2bf(v.w);
    *(ushort4*)(out + i) = o;
  }
}

// ------------------------------------------------- transpose+cast: [R][C]f32 -> [C][R]bf16
__global__ __launch_bounds__(256) void transpose_cast_k(const float* __restrict__ in,
                                                        u16* __restrict__ out,
                                                        int R, int C) {
  __shared__ float tile[32][33];
  int c0 = blockIdx.x * 32, r0 = blockIdx.y * 32;
  int j = threadIdx.x & 31, i0 = threadIdx.x >> 5;
#pragma unroll
  for (int p = 0; p < 4; ++p) {
    int i = i0 + p * 8;
    tile[i][j] = in[(size_t)(r0 + i) * C + (c0 + j)];
  }
  __syncthreads();
#pragma unroll
  for (int p = 0; p < 4; ++p) {
    int i = i0 + p * 8;
    out[(size_t)(c0 + i) * R + (r0 + j)] = f2bf(tile[j][i]);
  }
}

// ------------------------------------------------------------------ GEMM (B^T input)
// C[M][N] = A[M][K] @ Bt[N][K], bf16 in, fp32 accum. TMx128 tile, BK=64.
// EPI==1: store f32 (acc + bias[col] + resid[row][col]).
// EPI==2: QKV split: cols<2048 -> Cb (stride 2048, Q|K packed);
//         cols>=2048 are V -> transposed store into Vt[bh][d][l].
template <int EPI, int TM>
__global__ __launch_bounds__(256) void gemm_bt(const u16* __restrict__ A,
                                               const u16* __restrict__ Bt,
                                               u16* __restrict__ Cb,
                                               float* __restrict__ Cf,
                                               const float* __restrict__ bias,
                                               const float* __restrict__ resid,
                                               u16* __restrict__ Vt,
                                               int M, int N, int K) {
  constexpr int MI = TM / 32;  // A-frags per wave (wave m-extent = TM/2)
  __shared__ alignas(16) u16 As[TM * 64];
  __shared__ alignas(16) u16 Bs[128 * 64];
  const int tid = threadIdx.x;
  const int lane = tid & 63;
  const int w = tid >> 6;
  const int wm = w >> 1, wn = w & 1;
  const int m0 = blockIdx.y * TM, n0 = blockIdx.x * 128;
  const int ln = lane & 15, qq = lane >> 4;
  const f32x4 zero4 = {0.f, 0.f, 0.f, 0.f};

  f32x4 acc[MI][4];
#pragma unroll
  for (int i = 0; i < MI; ++i)
#pragma unroll
    for (int j = 0; j < 4; ++j) acc[i][j] = zero4;

  for (int kt = 0; kt < K; kt += 64) {
    __syncthreads();
    // rows of 64 bf16 = 8 chunks of 16B; dest chunk d holds global chunk
    // d ^ (r&7) so frag reads (chunk (ks*4+qq)^(r&7)) spread all banks.
#pragma unroll
    for (int p = 0; p < TM / 32; ++p) {
      int t = p * 256 + tid;
      int r = t >> 3;
      int cl = (t & 7) ^ (r & 7);
      load_lds16(A + (size_t)(m0 + r) * K + kt + cl * 8,
                 (char*)As + (p * 256 + w * 64) * 16);
    }
#pragma unroll
    for (int p = 0; p < 4; ++p) {
      int t = p * 256 + tid;
      int r = t >> 3;
      int cl = (t & 7) ^ (r & 7);
      load_lds16(Bt + (size_t)(n0 + r) * K + kt + cl * 8,
                 (char*)Bs + (p * 256 + w * 64) * 16);
    }
    __syncthreads();
#pragma unroll
    for (int ks = 0; ks < 2; ++ks) {
      bf16x8 af[MI], bfr[4];
#pragma unroll
      for (int i = 0; i < MI; ++i) {
        int ra = wm * (TM / 2) + i * 16 + ln;
        af[i] = *(const bf16x8*)(As + (ra * 8 + ((ks * 4 + qq) ^ (ra & 7))) * 8);
      }
#pragma unroll
      for (int j = 0; j < 4; ++j) {
        int rb = wn * 64 + j * 16 + ln;
        bfr[j] = *(const bf16x8*)(Bs + (rb * 8 + ((ks * 4 + qq) ^ (rb & 7))) * 8);
      }
#pragma unroll
      for (int i = 0; i < MI; ++i)
#pragma unroll
        for (int j = 0; j < 4; ++j)
          acc[i][j] = __builtin_amdgcn_mfma_f32_16x16x32_bf16(af[i], bfr[j],
                                                              acc[i][j], 0, 0, 0);
    }
  }

  // C/D layout (m89-verified): col = lane&15, row = (lane>>4)*4 + reg
#pragma unroll
  for (int i = 0; i < MI; ++i) {
#pragma unroll
    for (int j = 0; j < 4; ++j) {
      int col = n0 + wn * 64 + j * 16 + ln;
      if (EPI == 1) {
#pragma unroll
        for (int rr = 0; rr < 4; ++rr) {
          int row = m0 + wm * (TM / 2) + i * 16 + qq * 4 + rr;
          Cf[(size_t)row * N + col] =
              acc[i][j][rr] + bias[col] + resid[(size_t)row * N + col];
        }
      } else {  // EPI == 2
        if (col < 2048) {
#pragma unroll
          for (int rr = 0; rr < 4; ++rr) {
            int row = m0 + wm * (TM / 2) + i * 16 + qq * 4 + rr;
            Cb[(size_t)row * 2048 + col] = f2bf(acc[i][j][rr]);
          }
        } else {
          // V column: store transposed Vt[(b*16+h)*64+d][l], 4 consecutive l
          int dg = col - 2048;
          int hh = dg >> 6, dd = dg & 63;
          int l0 = (m0 & 2047) + wm * (TM / 2) + i * 16 + qq * 4;
          int bb = m0 >> 11;
          ushort4 pk;
          pk.x = f2bf(acc[i][j][0]); pk.y = f2bf(acc[i][j][1]);
          pk.z = f2bf(acc[i][j][2]); pk.w = f2bf(acc[i][j][3]);
          *(ushort4*)(Vt + (((size_t)bb * 16 + hh) * 64 + dd) * 2048 + l0) = pk;
        }
      }
    }
  }
}

// ------------------------------------------------------------------ flash attention (S^T form)
// R10 = R7 byte-identical EXCEPT the block-index remap (single variable):
//   blockIdx = qt*32 + bh  ->  blockIdx%8 = bh%8, so all 32 q-blocks of one
//   (b,h) share an XCD; per-XCD K/V set = 4 heads x 512KB = 2MB < 4MB L2.
// Static softmax (R7): no online max; per-lane partial sums, 2 shfls at end.
__global__ __launch_bounds__(256) void attn_fused(const u16* __restrict__ qk,
                                                  const u16* __restrict__ vt,
                                                  u16* __restrict__ outp) {
  const int bh = blockIdx.x & 31;   // b*16+h  -> XCD group = bh%8
  const int qt = blockIdx.x >> 5;
  const int h = bh & 15;
  const int b = bh >> 4;
  const int tid = threadIdx.x;
  const int lane = tid & 63;
  const int w = tid >> 6;
  const int ln = lane & 15, q4 = lane >> 4;
  const int l7 = ln & 7;
  const f32x4 zero4 = {0.f, 0.f, 0.f, 0.f};

  __shared__ alignas(16) u16 Ks[64 * 64];     // [key][8 chunk swz c^(key&7)][8 d]
  __shared__ alignas(16) u16 Vs[64 * 64];     // [d][8 chunk swz c^(d&7)][8 key]
  __shared__ alignas(16) u16 Ps[4][16 * 72];  // per-wave P^T as [q][72] (8 pad)

  const size_t bh_tok = (size_t)b * LSEQ;
  const size_t vbase = ((size_t)b * 16 + h) * 64 * 2048;
  const int baseQ = h * HDIM;

  // Q fragment (B-operand: n=ln, k=q4*8+j (+32*ks)), scaled by log2e/8
  const float qscale = 0.125f * 1.44269504088896340736f;
  bf16x8 qf[2];
  {
    int row = qt * 64 + w * 16 + ln;
    const u16* p = qk + (bh_tok + row) * 2048 + baseQ;
#pragma unroll
    for (int ks = 0; ks < 2; ++ks) {
      bf16x8 v = *(const bf16x8*)(p + q4 * 8 + 32 * ks);
      bf16x8 o;
#pragma unroll
      for (int jj = 0; jj < 8; ++jj) {
        union { uint32_t u; float f; } cv; cv.u = ((uint32_t)(u16)v[jj]) << 16;
        o[jj] = (short)f2bf(cv.f * qscale);
      }
      qf[ks] = o;
    }
  }

  float lsum = 0.f;  // per-lane partial row sum (reduced once at the end)
  f32x4 o_acc[4];
#pragma unroll
  for (int dt = 0; dt < 4; ++dt) o_acc[dt] = zero4;

  u16* pw_base = &Ps[w][0];

  for (int jt = 0; jt < 32; ++jt) {
    const int key0 = jt * 64;
    __syncthreads();
    // DMA K tile [64 key][64 d] and V^T tile [64 d][64 key]; chunk swz c^(row&7)
#pragma unroll
    for (int iss = 0; iss < 2; ++iss) {
      int idx = iss * 256 + tid;
      int row = idx >> 3, c = idx & 7;
      int cl = c ^ (row & 7);
      load_lds16(qk + (bh_tok + key0 + row) * 2048 + 1024 + baseQ + cl * 8,
                 (char*)Ks + (iss * 256 + w * 64) * 16);
      load_lds16(vt + vbase + (size_t)row * 2048 + key0 + cl * 8,
                 (char*)Vs + (iss * 256 + w * 64) * 16);
    }
    __syncthreads();

    // S^T[key][q] = K·Q^T : 4 key-tiles, 2 k-steps over d
    f32x4 S[4];
#pragma unroll
    for (int kt = 0; kt < 4; ++kt) {
      f32x4 a = zero4;
#pragma unroll
      for (int ks = 0; ks < 2; ++ks) {
        bf16x8 kf = *(const bf16x8*)(
            Ks + (((kt * 16 + ln) * 8 + ((ks * 4 + q4) ^ l7)) * 8));
        a = __builtin_amdgcn_mfma_f32_16x16x32_bf16(kf, qf[ks], a, 0, 0, 0);
      }
      S[kt] = a;
    }

    // static softmax: P = 2^S, accumulate per-lane partial sums only
#pragma unroll
    for (int kt = 0; kt < 4; ++kt)
#pragma unroll
      for (int r = 0; r < 4; ++r) {
        float p = fast_exp2(S[kt][r]);
        S[kt][r] = p;
        lsum += p;
      }

    // P^T (C-layout) -> per-wave LDS [q][key] rowstride 72, b64 writes
#pragma unroll
    for (int kt = 0; kt < 4; ++kt) {
      uint2 pd;
      pd.x = pack_bf2(S[kt][0], S[kt][1]);
      pd.y = pack_bf2(S[kt][2], S[kt][3]);
      *(uint2*)(pw_base + ln * 72 + kt * 16 + q4 * 4) = pd;
    }
    asm volatile("s_waitcnt lgkmcnt(0)" ::: "memory");  // wave-local W->R fence

    bf16x8 pf0 = *(const bf16x8*)(pw_base + ln * 72 + 0 * 32 + q4 * 8);
    bf16x8 pf1 = *(const bf16x8*)(pw_base + ln * 72 + 1 * 32 + q4 * 8);

    // O^T[d][q] += V^T·P^T
#pragma unroll
    for (int dt = 0; dt < 4; ++dt) {
      bf16x8 va0 = *(const bf16x8*)(
          Vs + (((dt * 16 + ln) * 8 + ((0 * 4 + q4) ^ l7)) * 8));
      o_acc[dt] = __builtin_amdgcn_mfma_f32_16x16x32_bf16(va0, pf0, o_acc[dt], 0, 0, 0);
      bf16x8 va1 = *(const bf16x8*)(
          Vs + (((dt * 16 + ln) * 8 + ((1 * 4 + q4) ^ l7)) * 8));
      o_acc[dt] = __builtin_amdgcn_mfma_f32_16x16x32_bf16(va1, pf1, o_acc[dt], 0, 0, 0);
    }
  }

  // final row-sum reduction (deferred): lanes 16/32 hold other key subsets
  lsum += __shfl_xor(lsum, 16);
  lsum += __shfl_xor(lsum, 32);
  float rl = 1.0f / lsum;

  // epilogue: O^T -> per-wave LDS [q][d] -> coalesced rows out
  asm volatile("s_waitcnt lgkmcnt(0)" ::: "memory");
#pragma unroll
  for (int dt = 0; dt < 4; ++dt) {
    uint2 pd;
    pd.x = pack_bf2(o_acc[dt][0] * rl, o_acc[dt][1] * rl);
    pd.y = pack_bf2(o_acc[dt][2] * rl, o_acc[dt][3] * rl);
    *(uint2*)(pw_base + ln * 72 + dt * 16 + q4 * 4) = pd;
  }
  asm volatile("s_waitcnt lgkmcnt(0)" ::: "memory");
  // full-coverage read-out: 2 passes x 64 lanes x 8 u16 = 16 tokens x 64 d
#pragma unroll
  for (int half = 0; half < 2; ++half) {
    int rr = half * 8 + (lane >> 3);
    int ch = lane & 7;
    bf16x8 rowv = *(const bf16x8*)(pw_base + rr * 72 + ch * 8);
    int tok = qt * 64 + w * 16 + rr;
    *(bf16x8*)(outp + (bh_tok + tok) * 1024 + baseQ + ch * 8) = rowv;
  }
}

// ------------------------------------------------------------------ LayerNorm rows
// one wave per row, 4 rows/block, shuffle-only reduction (no barrier).
__global__ __launch_bounds__(256) void ln_k(const float* __restrict__ res,
                                            const float* __restrict__ gamma,
                                            const float* __restrict__ beta,
                                            float* __restrict__ out) {
  int w = threadIdx.x >> 6, lane = threadIdx.x & 63;
  int row = blockIdx.x * 4 + w;
  const float* r = res + (size_t)row * DIMC;
  float4 v[4];
  float s = 0.f, ss = 0.f;
#pragma unroll
  for (int p = 0; p < 4; ++p) {
    v[p] = *(const float4*)(r + (p * 64 + lane) * 4);
    s += v[p].x + v[p].y + v[p].z + v[p].w;
    ss += v[p].x * v[p].x + v[p].y * v[p].y + v[p].z * v[p].z + v[p].w * v[p].w;
  }
#pragma unroll
  for (int off = 1; off < 64; off <<= 1) {
    s += __shfl_xor(s, off);
    ss += __shfl_xor(ss, off);
  }
  float mean = s * (1.0f / DIMC);
  float var = ss * (1.0f / DIMC) - mean * mean;
  float inv = rsqrtf(var + 1e-5f);
#pragma unroll
  for (int p = 0; p < 4; ++p) {
    int c = (p * 64 + lane) * 4;
    float4 g = *(const float4*)(gamma + c);
    float4 bt = *(const float4*)(beta + c);
    float4 o;
    o.x = (v[p].x - mean) * inv * g.x + bt.x;
    o.y = (v[p].y - mean) * inv * g.y + bt.y;
    o.z = (v[p].z - mean) * inv * g.z + bt.z;
    o.w = (v[p].w - mean) * inv * g.w + bt.w;
    *(float4*)(out + (size_t)row * DIMC + c) = o;
  }
}

extern "C" void kernel_launch(void* const* d_in, const int* in_sizes, int n_in,
                              void* d_out, int out_size, void* d_ws, size_t ws_size,
                              hipStream_t stream) {
  const float* x = (const float*)d_in[0];
  const float* w_qkv = (const float*)d_in[1];
  const float* w_out = (const float*)d_in[2];
  const float* b_out = (const float*)d_in[3];
  const float* gamma = (const float*)d_in[4];
  const float* beta = (const float*)d_in[5];
  float* outp = (float*)d_out;
  char* ws = (char*)d_ws;

  // ws layout (38 MB), aliasing by liveness:
  //   [0,8M):   xb (bf16 x)         -> attnout after GEMM1
  //   [8,14M):  wqkvT               -> woutT after GEMM1
  //   [14,30M): qk (bf16 4096x2048) -> res (f32 16MB) after attn
  //   [30,38M): vt (bf16 32x64x2048, V pre-transposed)
  u16* xb = (u16*)(ws);
  u16* wqkvT = (u16*)(ws + ((size_t)8 << 20));
  u16* qk = (u16*)(ws + ((size_t)14 << 20));
  u16* vt = (u16*)(ws + ((size_t)30 << 20));
  u16* attnout = (u16*)(ws);
  u16* woutT = (u16*)(ws + ((size_t)8 << 20));
  float* res = (float*)(ws + ((size_t)14 << 20));

  cast_bf16_k<<<4096, 256, 0, stream>>>(x, xb, BLM * DIMC);
  transpose_cast_k<<<dim3(96, 32), 256, 0, stream>>>(w_qkv, wqkvT, 1024, 3072);
  gemm_bt<2, 128><<<dim3(24, 32), 256, 0, stream>>>(xb, wqkvT, qk, nullptr,
                                                    nullptr, nullptr, vt,
                                                    BLM, 3072, 1024);
  transpose_cast_k<<<dim3(32, 32), 256, 0, stream>>>(w_out, woutT, 1024, 1024);
  attn_fused<<<1024, 256, 0, stream>>>(qk, vt, attnout);
  gemm_bt<1, 64><<<dim3(8, 64), 256, 0, stream>>>(attnout, woutT, nullptr, res,
                                                  b_out, x, nullptr,
                                                  BLM, 1024, 1024);
  ln_k<<<1024, 256, 0, stream>>>(res, gamma, beta, outp);
}

// Round 12
// 203.589 us; speedup vs baseline: 1.0875x; 1.0291x over previous
//
#include <hip/hip_runtime.h>
#include <hip/hip_bf16.h>
#include <stdint.h>

// Problem constants (fixed-shape problem)
#define HEADS 16
#define HDIM  64
#define DIMC  1024
#define INNER 1024
#define LSEQ  2048
#define BLM   4096   // B*L

typedef unsigned short u16;
typedef __attribute__((ext_vector_type(8))) short bf16x8;  // 8 bf16 = 4 VGPRs
typedef __attribute__((ext_vector_type(4))) float f32x4;

__device__ __forceinline__ u16 f2bf(float f) {
  union { float f; uint32_t u; } v; v.f = f;
  uint32_t u = v.u;
  return (u16)((u + 0x7fffu + ((u >> 16) & 1u)) >> 16);  // RNE
}
__device__ __forceinline__ uint32_t pack_bf2(float a, float b) {
  float2 f2; f2.x = a; f2.y = b;
  __hip_bfloat162 t = __float22bfloat162_rn(f2);
  union { __hip_bfloat162 h; uint32_t u; } c; c.h = t; return c.u;
}
// raw quarter-rate HW exp2 — avoids OCML's precise-path polynomial
__device__ __forceinline__ float fast_exp2(float x) {
  float r; asm("v_exp_f32 %0, %1" : "=v"(r) : "v"(x)); return r;
}

// async global->LDS, 16B per lane; LDS dest = wave-uniform base + lane*16
__device__ __forceinline__ void load_lds16(const void* g, void* l) {
  __builtin_amdgcn_global_load_lds(
      (const __attribute__((address_space(1))) uint32_t*)g,
      (__attribute__((address_space(3))) uint32_t*)l, 16, 0, 0);
}

// --------------------------------------------------- fused prep (1 launch):
// blocks [0,4096): cast x f32->bf16
// blocks [4096,7168): transpose+cast w_qkv [1024][3072] -> [3072][1024]
// NOTE: w_out transpose is NOT fused here. woutT aliases wqkvT's ws region
// and may only be written AFTER gemm1 has consumed wqkvT — writing it in
// prep clobbered the Q-columns of wqkvT (the R9/R11 absmax-0.316 bug).
__global__ __launch_bounds__(256) void prep_k(const float* __restrict__ x,
                                              const float* __restrict__ w_qkv,
                                              u16* __restrict__ xb,
                                              u16* __restrict__ wqkvT) {
  __shared__ float tile[32][33];
  int bid = blockIdx.x;
  if (bid < 4096) {
    int i = (bid * 256 + threadIdx.x) * 4;
    float4 v = *(const float4*)(x + i);
    ushort4 o;
    o.x = f2bf(v.x); o.y = f2bf(v.y); o.z = f2bf(v.z); o.w = f2bf(v.w);
    *(ushort4*)(xb + i) = o;
    return;
  }
  int idx = bid - 4096;
  int bx = idx % 96, by = idx / 96;   // C=3072 -> 96 col-tiles, R=1024 -> 32 row-tiles
  int c0 = bx * 32, r0 = by * 32;
  int j = threadIdx.x & 31, i0 = threadIdx.x >> 5;
#pragma unroll
  for (int p = 0; p < 4; ++p) {
    int i = i0 + p * 8;
    tile[i][j] = w_qkv[(size_t)(r0 + i) * 3072 + (c0 + j)];
  }
  __syncthreads();
#pragma unroll
  for (int p = 0; p < 4; ++p) {
    int i = i0 + p * 8;
    wqkvT[(size_t)(c0 + i) * 1024 + (r0 + j)] = f2bf(tile[j][i]);
  }
}

// ------------------------------------------------- transpose+cast: [R][C]f32 -> [C][R]bf16
__global__ __launch_bounds__(256) void transpose_cast_k(const float* __restrict__ in,
                                                        u16* __restrict__ out,
                                                        int R, int C) {
  __shared__ float tile[32][33];
  int c0 = blockIdx.x * 32, r0 = blockIdx.y * 32;
  int j = threadIdx.x & 31, i0 = threadIdx.x >> 5;
#pragma unroll
  for (int p = 0; p < 4; ++p) {
    int i = i0 + p * 8;
    tile[i][j] = in[(size_t)(r0 + i) * C + (c0 + j)];
  }
  __syncthreads();
#pragma unroll
  for (int p = 0; p < 4; ++p) {
    int i = i0 + p * 8;
    out[(size_t)(c0 + i) * R + (r0 + j)] = f2bf(tile[j][i]);
  }
}

// ------------------------------------------------------------------ GEMM (B^T input)
// C[M][N] = A[M][K] @ Bt[N][K], bf16 in, fp32 accum. TMx128 tile, BK=64.
// EPI==1: store f32 (acc + bias[col] + resid[row][col]).
// EPI==2: QKV split: cols<2048 -> Cb (stride 2048, Q|K packed);
//         cols>=2048 are V -> transposed store into Vt[bh][d][l].
template <int EPI, int TM>
__global__ __launch_bounds__(256) void gemm_bt(const u16* __restrict__ A,
                                               const u16* __restrict__ Bt,
                                               u16* __restrict__ Cb,
                                               float* __restrict__ Cf,
                                               const float* __restrict__ bias,
                                               const float* __restrict__ resid,
                                               u16* __restrict__ Vt,
                                               int M, int N, int K) {
  constexpr int MI = TM / 32;  // A-frags per wave (wave m-extent = TM/2)
  __shared__ alignas(16) u16 As[TM * 64];
  __shared__ alignas(16) u16 Bs[128 * 64];
  const int tid = threadIdx.x;
  const int lane = tid & 63;
  const int w = tid >> 6;
  const int wm = w >> 1, wn = w & 1;
  const int m0 = blockIdx.y * TM, n0 = blockIdx.x * 128;
  const int ln = lane & 15, qq = lane >> 4;
  const f32x4 zero4 = {0.f, 0.f, 0.f, 0.f};

  f32x4 acc[MI][4];
#pragma unroll
  for (int i = 0; i < MI; ++i)
#pragma unroll
    for (int j = 0; j < 4; ++j) acc[i][j] = zero4;

  for (int kt = 0; kt < K; kt += 64) {
    __syncthreads();
    // rows of 64 bf16 = 8 chunks of 16B; dest chunk d holds global chunk
    // d ^ (r&7) so frag reads (chunk (ks*4+qq)^(r&7)) spread all banks.
#pragma unroll
    for (int p = 0; p < TM / 32; ++p) {
      int t = p * 256 + tid;
      int r = t >> 3;
      int cl = (t & 7) ^ (r & 7);
      load_lds16(A + (size_t)(m0 + r) * K + kt + cl * 8,
                 (char*)As + (p * 256 + w * 64) * 16);
    }
#pragma unroll
    for (int p = 0; p < 4; ++p) {
      int t = p * 256 + tid;
      int r = t >> 3;
      int cl = (t & 7) ^ (r & 7);
      load_lds16(Bt + (size_t)(n0 + r) * K + kt + cl * 8,
                 (char*)Bs + (p * 256 + w * 64) * 16);
    }
    __syncthreads();
#pragma unroll
    for (int ks = 0; ks < 2; ++ks) {
      bf16x8 af[MI], bfr[4];
#pragma unroll
      for (int i = 0; i < MI; ++i) {
        int ra = wm * (TM / 2) + i * 16 + ln;
        af[i] = *(const bf16x8*)(As + (ra * 8 + ((ks * 4 + qq) ^ (ra & 7))) * 8);
      }
#pragma unroll
      for (int j = 0; j < 4; ++j) {
        int rb = wn * 64 + j * 16 + ln;
        bfr[j] = *(const bf16x8*)(Bs + (rb * 8 + ((ks * 4 + qq) ^ (rb & 7))) * 8);
      }
#pragma unroll
      for (int i = 0; i < MI; ++i)
#pragma unroll
        for (int j = 0; j < 4; ++j)
          acc[i][j] = __builtin_amdgcn_mfma_f32_16x16x32_bf16(af[i], bfr[j],
                                                              acc[i][j], 0, 0, 0);
    }
  }

  // C/D layout (m89-verified): col = lane&15, row = (lane>>4)*4 + reg
#pragma unroll
  for (int i = 0; i < MI; ++i) {
#pragma unroll
    for (int j = 0; j < 4; ++j) {
      int col = n0 + wn * 64 + j * 16 + ln;
      if (EPI == 1) {
#pragma unroll
        for (int rr = 0; rr < 4; ++rr) {
          int row = m0 + wm * (TM / 2) + i * 16 + qq * 4 + rr;
          Cf[(size_t)row * N + col] =
              acc[i][j][rr] + bias[col] + resid[(size_t)row * N + col];
        }
      } else {  // EPI == 2
        if (col < 2048) {
#pragma unroll
          for (int rr = 0; rr < 4; ++rr) {
            int row = m0 + wm * (TM / 2) + i * 16 + qq * 4 + rr;
            Cb[(size_t)row * 2048 + col] = f2bf(acc[i][j][rr]);
          }
        } else {
          // V column: store transposed Vt[(b*16+h)*64+d][l], 4 consecutive l
          int dg = col - 2048;
          int hh = dg >> 6, dd = dg & 63;
          int l0 = (m0 & 2047) + wm * (TM / 2) + i * 16 + qq * 4;
          int bb = m0 >> 11;
          ushort4 pk;
          pk.x = f2bf(acc[i][j][0]); pk.y = f2bf(acc[i][j][1]);
          pk.z = f2bf(acc[i][j][2]); pk.w = f2bf(acc[i][j][3]);
          *(ushort4*)(Vt + (((size_t)bb * 16 + hh) * 64 + dd) * 2048 + l0) = pk;
        }
      }
    }
  }
}

// ------------------------------------------------------------------ flash attention (S^T form)
// R12 attn = R10 (XCD remap: blockIdx = qt*32+bh -> FETCH 69.7->12.3 MB,
// measured) + R8's P-buffer XOR unit-swizzle (conflicts 3.24M->2.16M,
// validated in R8): Ps[16][64] per wave, unit(16B) u' = u ^ (q&7).
// Static softmax; per-lane partial sums, 2 shfls at the end.
__global__ __launch_bounds__(256) void attn_fused(const u16* __restrict__ qk,
                                                  const u16* __restrict__ vt,
                                                  u16* __restrict__ outp) {
  const int bh = blockIdx.x & 31;   // b*16+h  -> XCD group = bh%8
  const int qt = blockIdx.x >> 5;
  const int h = bh & 15;
  const int b = bh >> 4;
  const int tid = threadIdx.x;
  const int lane = tid & 63;
  const int w = tid >> 6;
  const int ln = lane & 15, q4 = lane >> 4;
  const int l7 = ln & 7;
  const f32x4 zero4 = {0.f, 0.f, 0.f, 0.f};

  __shared__ alignas(16) u16 Ks[64 * 64];     // [key][8 chunk swz c^(key&7)][8 d]
  __shared__ alignas(16) u16 Vs[64 * 64];     // [d][8 chunk swz c^(d&7)][8 key]
  __shared__ alignas(16) u16 Ps[4][16 * 64];  // per-wave P^T, XOR unit-swizzled

  const size_t bh_tok = (size_t)b * LSEQ;
  const size_t vbase = ((size_t)b * 16 + h) * 64 * 2048;
  const int baseQ = h * HDIM;

  // Q fragment (B-operand: n=ln, k=q4*8+j (+32*ks)), scaled by log2e/8
  const float qscale = 0.125f * 1.44269504088896340736f;
  bf16x8 qf[2];
  {
    int row = qt * 64 + w * 16 + ln;
    const u16* p = qk + (bh_tok + row) * 2048 + baseQ;
#pragma unroll
    for (int ks = 0; ks < 2; ++ks) {
      bf16x8 v = *(const bf16x8*)(p + q4 * 8 + 32 * ks);
      bf16x8 o;
#pragma unroll
      for (int jj = 0; jj < 8; ++jj) {
        union { uint32_t u; float f; } cv; cv.u = ((uint32_t)(u16)v[jj]) << 16;
        o[jj] = (short)f2bf(cv.f * qscale);
      }
      qf[ks] = o;
    }
  }

  float lsum = 0.f;  // per-lane partial row sum (reduced once at the end)
  f32x4 o_acc[4];
#pragma unroll
  for (int dt = 0; dt < 4; ++dt) o_acc[dt] = zero4;

  u16* pw_base = &Ps[w][0];

  for (int jt = 0; jt < 32; ++jt) {
    const int key0 = jt * 64;
    __syncthreads();
    // DMA K tile [64 key][64 d] and V^T tile [64 d][64 key]; chunk swz c^(row&7)
#pragma unroll
    for (int iss = 0; iss < 2; ++iss) {
      int idx = iss * 256 + tid;
      int row = idx >> 3, c = idx & 7;
      int cl = c ^ (row & 7);
      load_lds16(qk + (bh_tok + key0 + row) * 2048 + 1024 + baseQ + cl * 8,
                 (char*)Ks + (iss * 256 + w * 64) * 16);
      load_lds16(vt + vbase + (size_t)row * 2048 + key0 + cl * 8,
                 (char*)Vs + (iss * 256 + w * 64) * 16);
    }
    __syncthreads();

    // S^T[key][q] = K·Q^T : 4 key-tiles, 2 k-steps over d
    f32x4 S[4];
#pragma unroll
    for (int kt = 0; kt < 4; ++kt) {
      f32x4 a = zero4;
#pragma unroll
      for (int ks = 0; ks < 2; ++ks) {
        bf16x8 kf = *(const bf16x8*)(
            Ks + (((kt * 16 + ln) * 8 + ((ks * 4 + q4) ^ l7)) * 8));
        a = __builtin_amdgcn_mfma_f32_16x16x32_bf16(kf, qf[ks], a, 0, 0, 0);
      }
      S[kt] = a;
    }

    // static softmax: P = 2^S, accumulate per-lane partial sums only
#pragma unroll
    for (int kt = 0; kt < 4; ++kt)
#pragma unroll
      for (int r = 0; r < 4; ++r) {
        float p = fast_exp2(S[kt][r]);
        S[kt][r] = p;
        lsum += p;
      }

    // P^T (C-layout) -> per-wave LDS [q=ln][key], unit(16B) XOR-swizzled
#pragma unroll
    for (int kt = 0; kt < 4; ++kt) {
      uint2 pd;
      pd.x = pack_bf2(S[kt][0], S[kt][1]);
      pd.y = pack_bf2(S[kt][2], S[kt][3]);
      int u = kt * 2 + (q4 >> 1);
      *(uint2*)(pw_base + ln * 64 + ((u ^ l7) * 8) + (q4 & 1) * 4) = pd;
    }
    asm volatile("s_waitcnt lgkmcnt(0)" ::: "memory");  // wave-local W->R fence

    bf16x8 pf0 = *(const bf16x8*)(pw_base + ln * 64 + (((0 * 4 + q4) ^ l7) * 8));
    bf16x8 pf1 = *(const bf16x8*)(pw_base + ln * 64 + (((1 * 4 + q4) ^ l7) * 8));

    // O^T[d][q] += V^T·P^T
#pragma unroll
    for (int dt = 0; dt < 4; ++dt) {
      bf16x8 va0 = *(const bf16x8*)(
          Vs + (((dt * 16 + ln) * 8 + ((0 * 4 + q4) ^ l7)) * 8));
      o_acc[dt] = __builtin_amdgcn_mfma_f32_16x16x32_bf16(va0, pf0, o_acc[dt], 0, 0, 0);
      bf16x8 va1 = *(const bf16x8*)(
          Vs + (((dt * 16 + ln) * 8 + ((1 * 4 + q4) ^ l7)) * 8));
      o_acc[dt] = __builtin_amdgcn_mfma_f32_16x16x32_bf16(va1, pf1, o_acc[dt], 0, 0, 0);
    }
  }

  // final row-sum reduction (deferred): lanes 16/32 hold other key subsets
  lsum += __shfl_xor(lsum, 16);
  lsum += __shfl_xor(lsum, 32);
  float rl = 1.0f / lsum;

  // epilogue: O^T -> per-wave LDS [q=ln][d] (same unit swizzle) -> rows out
  asm volatile("s_waitcnt lgkmcnt(0)" ::: "memory");
#pragma unroll
  for (int dt = 0; dt < 4; ++dt) {
    uint2 pd;
    pd.x = pack_bf2(o_acc[dt][0] * rl, o_acc[dt][1] * rl);
    pd.y = pack_bf2(o_acc[dt][2] * rl, o_acc[dt][3] * rl);
    int u = dt * 2 + (q4 >> 1);
    *(uint2*)(pw_base + ln * 64 + ((u ^ l7) * 8) + (q4 & 1) * 4) = pd;
  }
  asm volatile("s_waitcnt lgkmcnt(0)" ::: "memory");
  // full-coverage read-out: 2 passes x 64 lanes x 8 u16 = 16 tokens x 64 d
#pragma unroll
  for (int half = 0; half < 2; ++half) {
    int rr = half * 8 + (lane >> 3);
    int ch = lane & 7;
    bf16x8 rowv = *(const bf16x8*)(pw_base + rr * 64 + ((ch ^ (rr & 7)) * 8));
    int tok = qt * 64 + w * 16 + rr;
    *(bf16x8*)(outp + (bh_tok + tok) * 1024 + baseQ + ch * 8) = rowv;
  }
}

// ------------------------------------------------------------------ LayerNorm rows
// one wave per row, 4 rows/block, shuffle-only reduction (no barrier).
__global__ __launch_bounds__(256) void ln_k(const float* __restrict__ res,
                                            const float* __restrict__ gamma,
                                            const float* __restrict__ beta,
                                            float* __restrict__ out) {
  int w = threadIdx.x >> 6, lane = threadIdx.x & 63;
  int row = blockIdx.x * 4 + w;
  const float* r = res + (size_t)row * DIMC;
  float4 v[4];
  float s = 0.f, ss = 0.f;
#pragma unroll
  for (int p = 0; p < 4; ++p) {
    v[p] = *(const float4*)(r + (p * 64 + lane) * 4);
    s += v[p].x + v[p].y + v[p].z + v[p].w;
    ss += v[p].x * v[p].x + v[p].y * v[p].y + v[p].z * v[p].z + v[p].w * v[p].w;
  }
#pragma unroll
  for (int off = 1; off < 64; off <<= 1) {
    s += __shfl_xor(s, off);
    ss += __shfl_xor(ss, off);
  }
  float mean = s * (1.0f / DIMC);
  float var = ss * (1.0f / DIMC) - mean * mean;
  float inv = rsqrtf(var + 1e-5f);
#pragma unroll
  for (int p = 0; p < 4; ++p) {
    int c = (p * 64 + lane) * 4;
    float4 g = *(const float4*)(gamma + c);
    float4 bt = *(const float4*)(beta + c);
    float4 o;
    o.x = (v[p].x - mean) * inv * g.x + bt.x;
    o.y = (v[p].y - mean) * inv * g.y + bt.y;
    o.z = (v[p].z - mean) * inv * g.z + bt.z;
    o.w = (v[p].w - mean) * inv * g.w + bt.w;
    *(float4*)(out + (size_t)row * DIMC + c) = o;
  }
}

extern "C" void kernel_launch(void* const* d_in, const int* in_sizes, int n_in,
                              void* d_out, int out_size, void* d_ws, size_t ws_size,
                              hipStream_t stream) {
  const float* x = (const float*)d_in[0];
  const float* w_qkv = (const float*)d_in[1];
  const float* w_out = (const float*)d_in[2];
  const float* b_out = (const float*)d_in[3];
  const float* gamma = (const float*)d_in[4];
  const float* beta = (const float*)d_in[5];
  float* outp = (float*)d_out;
  char* ws = (char*)d_ws;

  // ws layout (38 MB), aliasing by liveness (ORDER-SENSITIVE):
  //   [0,8M):   xb (bf16 x)         -> attnout after GEMM1
  //   [8,14M):  wqkvT               -> woutT ONLY after GEMM1 (R9/R11 bug)
  //   [14,30M): qk (bf16 4096x2048) -> res (f32 16MB) after attn
  //   [30,38M): vt (bf16 32x64x2048, V pre-transposed)
  u16* xb = (u16*)(ws);
  u16* wqkvT = (u16*)(ws + ((size_t)8 << 20));
  u16* qk = (u16*)(ws + ((size_t)14 << 20));
  u16* vt = (u16*)(ws + ((size_t)30 << 20));
  u16* attnout = (u16*)(ws);
  u16* woutT = (u16*)(ws + ((size_t)8 << 20));
  float* res = (float*)(ws + ((size_t)14 << 20));

  prep_k<<<7168, 256, 0, stream>>>(x, w_qkv, xb, wqkvT);
  gemm_bt<2, 128><<<dim3(24, 32), 256, 0, stream>>>(xb, wqkvT, qk, nullptr,
                                                    nullptr, nullptr, vt,
                                                    BLM, 3072, 1024);
  transpose_cast_k<<<dim3(32, 32), 256, 0, stream>>>(w_out, woutT, 1024, 1024);
  attn_fused<<<1024, 256, 0, stream>>>(qk, vt, attnout);
  gemm_bt<1, 64><<<dim3(8, 64), 256, 0, stream>>>(attnout, woutT, nullptr, res,
                                                  b_out, x, nullptr,
                                                  BLM, 1024, 1024);
  ln_k<<<1024, 256, 0, stream>>>(res, gamma, beta, outp);
}